// Round 2
// baseline (1221.666 us; speedup 1.0000x reference)
//
#include <hip/hip_runtime.h>
#include <hip/hip_cooperative_groups.h>
#include <stdint.h>
#include <stddef.h>

namespace cg = cooperative_groups;

#define DIN    512
#define BGR    1024
#define NGATE  2048   // 4*DIN
#define KQ     1024   // 2*DIN (q_star width)
#define DOUT   512
#define TSTEPS 6

typedef unsigned short ushort_t;
typedef short bf16x8 __attribute__((ext_vector_type(8)));
typedef unsigned short u16x8 __attribute__((ext_vector_type(8)));
typedef float f32x4 __attribute__((ext_vector_type(4)));

__device__ __forceinline__ float b2f(unsigned short u) {
    unsigned int i = ((unsigned int)u) << 16;
    float f;
    __builtin_memcpy(&f, &i, 4);
    return f;
}

__device__ __forceinline__ unsigned short f2b(float f) {
    unsigned int i;
    __builtin_memcpy(&i, &f, 4);
    unsigned int lsb = (i >> 16) & 1u;
    i += 0x7fffu + lsb;   // round-to-nearest-even
    return (unsigned short)(i >> 16);
}

__device__ __forceinline__ float fast_sigmoid(float v) {
    return 1.f / (1.f + __expf(-v));
}

__device__ __forceinline__ float fast_tanh(float v) {
    float t = fabsf(v);
    float e = __expf(-2.f * t);
    float r = (1.f - e) / (1.f + e);
    return v < 0.f ? -r : r;
}

// ---------------------------------------------------------------------------
// Dtype probe: flags[t]=1 if tensor t is f32, 0 if bf16.
// ---------------------------------------------------------------------------
__global__ void probe_dtypes(const ushort_t* x, const ushort_t* Wih,
                             const ushort_t* Whh, const ushort_t* bih,
                             const ushort_t* bhh, const ushort_t* Wpost,
                             const ushort_t* bpost, int* flags)
{
    __shared__ int cnt[7];
    const int tid = threadIdx.x;
    if (tid < 7) cnt[tid] = 0;
    __syncthreads();
    const int t = tid >> 5;
    const int l = tid & 31;
    if (t < 7) {
        const ushort_t* p = (t == 0) ? x : (t == 1) ? Wih : (t == 2) ? Whh
                          : (t == 3) ? bih : (t == 4) ? bhh
                          : (t == 5) ? Wpost : bpost;
        int good = 0;
        for (int i = 0; i < 4; i++) {
            ushort_t u = p[(l * 4 + i) * 2];
            int ex = (u >> 7) & 0xFF;
            if (ex == 0 || (ex >= 96 && ex <= 143)) good++;
        }
        atomicAdd(&cnt[t], good);
    }
    __syncthreads();
    if (tid < 7) flags[tid] = (cnt[tid] < 96) ? 1 : 0;
}

#define BM 64
#define BN 64
#define BK 32

// ---------------------------------------------------------------------------
// Plain GEMM 64x64 tile (final Wpost + relu only). Pipelined staging.
// ---------------------------------------------------------------------------
template <int MODE>
__global__ __launch_bounds__(256)
void gemm_bt(const ushort_t* __restrict__ Ag, const ushort_t* __restrict__ Bgm,
             const float* __restrict__ bias, float* __restrict__ Cout,
             int M, int N, int K)
{
    __shared__ __align__(16) ushort_t As[BM * BK];
    __shared__ __align__(16) ushort_t Bs[BN * BK];

    const int tid  = threadIdx.x;
    const int lane = tid & 63;
    const int w    = tid >> 6;
    const int wr   = w >> 1;
    const int wc   = w & 1;
    const int lrow = lane & 15;
    const int quad = lane >> 4;

    const int n0 = blockIdx.x * BN;
    const int m0 = blockIdx.y * BM;

    const int srow = tid >> 2;
    const int scol = (tid & 3) * 8;

    const ushort_t* aSrc = Ag  + (size_t)(m0 + srow) * K + scol;
    const ushort_t* bSrc = Bgm + (size_t)(n0 + srow) * K + scol;

    f32x4 acc[2][2];
#pragma unroll
    for (int i = 0; i < 2; i++)
#pragma unroll
        for (int j = 0; j < 2; j++)
            acc[i][j] = (f32x4){0.f, 0.f, 0.f, 0.f};

    bf16x8 av = *(const bf16x8*)(aSrc);
    bf16x8 bv = *(const bf16x8*)(bSrc);

    for (int kt = 0; kt < K; kt += BK) {
        __syncthreads();
        *(bf16x8*)&As[srow * BK + scol] = av;
        *(bf16x8*)&Bs[srow * BK + scol] = bv;
        if (kt + BK < K) {
            av = *(const bf16x8*)(aSrc + kt + BK);
            bv = *(const bf16x8*)(bSrc + kt + BK);
        }
        __syncthreads();

        bf16x8 af[2], bfr[2];
#pragma unroll
        for (int mi = 0; mi < 2; mi++)
            af[mi] = *(const bf16x8*)&As[(wr * 32 + mi * 16 + lrow) * BK + quad * 8];
#pragma unroll
        for (int ni = 0; ni < 2; ni++)
            bfr[ni] = *(const bf16x8*)&Bs[(wc * 32 + ni * 16 + lrow) * BK + quad * 8];

#pragma unroll
        for (int mi = 0; mi < 2; mi++)
#pragma unroll
            for (int ni = 0; ni < 2; ni++)
                acc[mi][ni] = __builtin_amdgcn_mfma_f32_16x16x32_bf16(
                    af[mi], bfr[ni], acc[mi][ni], 0, 0, 0);
    }

#pragma unroll
    for (int mi = 0; mi < 2; mi++) {
#pragma unroll
        for (int ni = 0; ni < 2; ni++) {
#pragma unroll
            for (int r = 0; r < 4; r++) {
                int gm = m0 + wr * 32 + mi * 16 + quad * 4 + r;
                int gn = n0 + wc * 32 + ni * 16 + lrow;
                float v = acc[mi][ni][r] + bias[gn];
                if (MODE == 1) {
                    if (!(v > 0.f) && (v == v)) v = 0.f;   // NaN-transparent relu
                }
                Cout[(size_t)gm * N + gn] = v;
            }
        }
    }
}

// ---------------------------------------------------------------------------
// Persistent cooperative kernel: the whole 6-step loop in ONE dispatch.
// 512 blocks x 256 threads = exactly 2 blocks/CU (guaranteed by
// __launch_bounds__(256,2): VGPR<=128, LDS 18.4KB).
// Per step: [grid.sync] gemm+cell phase (block = old (bx,by) tile)
//           [grid.sync] attn phase (block owns graphs 2*bid, 2*bid+1,
//           processed sequentially with the old 4-wave structure —
//           bit-identical numerics to the R1 kernel).
// t=0: h0/c0 from biases computed per block (z0 = bih+bhh, same all graphs).
// ---------------------------------------------------------------------------
__global__ __launch_bounds__(256, 2)
void fused_loop(const ushort_t* __restrict__ xraw,
                ushort_t* __restrict__ xb,        // may be null if !use_xb
                const int* __restrict__ offs,
                const ushort_t* __restrict__ Wg,  // gate-interleaved W'
                const float* __restrict__ bias2,  // gate-interleaved bias
                const ushort_t* __restrict__ bih,
                const ushort_t* __restrict__ bhh,
                float* __restrict__ c,
                float* __restrict__ H,
                ushort_t* __restrict__ A,
                const int* __restrict__ flags,
                int use_xb)
{
    cg::grid_group grid = cg::this_grid();
    const int bid  = blockIdx.x;     // 0..511
    const int tid  = threadIdx.x;
    const int lane = tid & 63;
    const int w    = tid >> 6;
    const int g0   = bid * 2;

    __shared__ __align__(16) ushort_t As[BM * BK];   // 4 KB
    __shared__ __align__(16) ushort_t Bs[BM * BK];   // 4 KB
    __shared__ float accL[4][DIN];                   // 8 KB
    __shared__ float mw[4], lw[4];
    __shared__ float h0sh[DIN];                      // 2 KB

    const int xf = flags[0];

    // ---- t=0 prologue: z0 = bih+bhh (identical for all graphs) ----
    {
        const int fbih = flags[3], fbhh = flags[4];
        for (int d = tid; d < DIN; d += 256) {
            float zi = fbih ? ((const float*)bih)[d] : b2f(bih[d]);
            zi      += fbhh ? ((const float*)bhh)[d] : b2f(bhh[d]);
            float zg = fbih ? ((const float*)bih)[2 * DIN + d] : b2f(bih[2 * DIN + d]);
            zg      += fbhh ? ((const float*)bhh)[2 * DIN + d] : b2f(bhh[2 * DIN + d]);
            float zo = fbih ? ((const float*)bih)[3 * DIN + d] : b2f(bih[3 * DIN + d]);
            zo      += fbhh ? ((const float*)bhh)[3 * DIN + d] : b2f(bhh[3 * DIN + d]);
            float c0 = fast_sigmoid(zi) * fast_tanh(zg);   // sig(zf)*c_prev = 0
            float h0 = fast_sigmoid(zo) * fast_tanh(c0);
            h0sh[d] = h0;
            c[(size_t)g0 * DIN + d]       = c0;
            c[(size_t)(g0 + 1) * DIN + d] = c0;
            ushort_t hb = f2b(h0);
            A[(size_t)g0 * KQ + d]       = hb;
            A[(size_t)(g0 + 1) * KQ + d] = hb;
        }
        __syncthreads();
    }

    const int lrow = lane & 15;
    const int quad = lane >> 4;
    const float NEG_INF = -__builtin_inff();

    for (int t = 0; t < TSTEPS; ++t) {
        if (t > 0) {
            grid.sync();
            // ---------------- GEMM + LSTM cell phase ----------------
            const int n0   = (bid & 31) * 64;    // gate-col block
            const int m0   = (bid >> 5) * 64;    // row block
            const int srow = tid >> 2;
            const int scol = (tid & 3) * 8;
            const ushort_t* aSrc = A  + (size_t)(m0 + srow) * KQ + scol;
            const ushort_t* bSrc = Wg + (size_t)(n0 + srow) * KQ + scol;

            f32x4 acc4[4];
#pragma unroll
            for (int ni = 0; ni < 4; ni++) acc4[ni] = (f32x4){0.f, 0.f, 0.f, 0.f};

            bf16x8 av = *(const bf16x8*)(aSrc);
            bf16x8 bv = *(const bf16x8*)(bSrc);

            for (int kt = 0; kt < KQ; kt += BK) {
                __syncthreads();
                *(bf16x8*)&As[srow * BK + scol] = av;
                *(bf16x8*)&Bs[srow * BK + scol] = bv;
                if (kt + BK < KQ) {              // prefetch next K-tile
                    av = *(const bf16x8*)(aSrc + kt + BK);
                    bv = *(const bf16x8*)(bSrc + kt + BK);
                }
                __syncthreads();

                bf16x8 af = *(const bf16x8*)&As[(w * 16 + lrow) * BK + quad * 8];
                bf16x8 bfr[4];
#pragma unroll
                for (int ni = 0; ni < 4; ni++)
                    bfr[ni] = *(const bf16x8*)&Bs[(ni * 16 + lrow) * BK + quad * 8];
#pragma unroll
                for (int ni = 0; ni < 4; ni++)
                    acc4[ni] = __builtin_amdgcn_mfma_f32_16x16x32_bf16(
                        af, bfr[ni], acc4[ni], 0, 0, 0);
            }

            // fused cell epilogue (D layout: row=quad*4+r, col=lrow)
            const int dd  = (bid & 31) * 16 + lrow;
            const float bi_ = bias2[n0 + lrow];
            const float bf_ = bias2[n0 + 16 + lrow];
            const float bg_ = bias2[n0 + 32 + lrow];
            const float bo_ = bias2[n0 + 48 + lrow];
#pragma unroll
            for (int r = 0; r < 4; r++) {
                const int gm = m0 + w * 16 + quad * 4 + r;
                float zi = acc4[0][r] + bi_;
                float zf = acc4[1][r] + bf_;
                float zg = acc4[2][r] + bg_;
                float zo = acc4[3][r] + bo_;
                size_t off = (size_t)gm * DIN + dd;
                float cc = c[off];
                cc = fast_sigmoid(zf) * cc + fast_sigmoid(zi) * fast_tanh(zg);
                float hh = fast_sigmoid(zo) * fast_tanh(cc);
                c[off] = cc;
                H[off] = hh;
            }
            grid.sync();
        }

        // ---------------- attention phase: 2 graphs sequentially ----------------
        // load mode: 0 = bf16 from xb; 1 = f32 from xraw; 2 = bf16 from xraw
        const int sel  = (use_xb && t > 0) ? 0 : (xf ? 1 : 2);
        const int wrxb = (use_xb && t == 0) ? 1 : 0;

        for (int gg = 0; gg < 2; ++gg) {
            const int b = g0 + gg;
            const float* hrow = H + (size_t)b * DIN;

            float q8[8];
            if (t == 0) {
#pragma unroll
                for (int j = 0; j < 8; j++) q8[j] = h0sh[lane * 8 + j];
            } else {
                f32x4 q0v = *(const f32x4*)(hrow + lane * 8);
                f32x4 q1v = *(const f32x4*)(hrow + lane * 8 + 4);
#pragma unroll
                for (int j = 0; j < 4; j++) { q8[j] = q0v[j]; q8[4 + j] = q1v[j]; }
                const int dq = tid * 2;                    // q = h into q_star
                A[(size_t)b * KQ + dq]     = f2b(hrow[dq]);
                A[(size_t)b * KQ + dq + 1] = f2b(hrow[dq + 1]);
            }

            const int s  = offs[b];
            const int en = offs[b + 1];

            float m = NEG_INF, l = 0.f;
            float acc[8];
#pragma unroll
            for (int j = 0; j < 8; j++) acc[j] = 0.f;

            auto load_row = [&](int n, float* v) {
                if (sel == 0) {
                    u16x8 xv = *(const u16x8*)(xb + (size_t)n * DIN + lane * 8);
#pragma unroll
                    for (int j = 0; j < 8; j++) v[j] = b2f(xv[j]);
                } else if (sel == 2) {
                    u16x8 xv = *(const u16x8*)(xraw + (size_t)n * DIN + lane * 8);
#pragma unroll
                    for (int j = 0; j < 8; j++) v[j] = b2f(xv[j]);
                    if (wrxb)
                        *(u16x8*)(xb + (size_t)n * DIN + lane * 8) = xv;
                } else {
                    const float* xp = (const float*)xraw;
                    f32x4 v0 = *(const f32x4*)(xp + (size_t)n * DIN + lane * 8);
                    f32x4 v1 = *(const f32x4*)(xp + (size_t)n * DIN + lane * 8 + 4);
#pragma unroll
                    for (int j = 0; j < 4; j++) { v[j] = v0[j]; v[4 + j] = v1[j]; }
                    if (wrxb) {
                        u16x8 o;
#pragma unroll
                        for (int j = 0; j < 8; j++) o[j] = f2b(v[j]);
                        *(u16x8*)(xb + (size_t)n * DIN + lane * 8) = o;
                    }
                }
            };

            auto update = [&](float e, const float* xv) {
                float mn = fmaxf(m, e);
                float al = __expf(m - mn);    // first node: exp(-inf)=0
                float pp = __expf(e - mn);
                l = l * al + pp;
#pragma unroll
                for (int j = 0; j < 8; j++) acc[j] = acc[j] * al + pp * xv[j];
                m = mn;
            };

            // pair-pipelined pass (rows n, n+4; prefetch n+8, n+12)
            float xa[8] = {0.f}, xc[8] = {0.f};
            int n = s + w;
            if (n < en)     load_row(n, xa);
            if (n + 4 < en) load_row(n + 4, xc);
            for (; n < en; n += 8) {
                float pa[8], pc[8];
                const int np = n + 8;
                if (np < en)     load_row(np, pa);
                if (np + 4 < en) load_row(np + 4, pc);

                float e1 = 0.f, e2 = 0.f;
#pragma unroll
                for (int j = 0; j < 8; j++) { e1 += q8[j] * xa[j]; e2 += q8[j] * xc[j]; }
#pragma unroll
                for (int off = 32; off > 0; off >>= 1) {
                    e1 += __shfl_xor(e1, off, 64);
                    e2 += __shfl_xor(e2, off, 64);
                }

                update(e1, xa);
                if (n + 4 < en) update(e2, xc);

#pragma unroll
                for (int j = 0; j < 8; j++) { xa[j] = pa[j]; xc[j] = pc[j]; }
            }

            // protect previous graph's merge reads of accL, then store partials
            __syncthreads();
            if (lane == 0) { mw[w] = m; lw[w] = l; }
#pragma unroll
            for (int j = 0; j < 8; j++) accL[w][lane * 8 + j] = acc[j];
            __syncthreads();

            // 4-wave flash combine (identical to previous kernel)
            const float M = fmaxf(fmaxf(mw[0], mw[1]), fmaxf(mw[2], mw[3]));
            const int d0 = tid * 2;
            float r0 = 0.f, r1 = 0.f, lt = 0.f;
#pragma unroll
            for (int ww = 0; ww < 4; ww++) {
                float mwv = mw[ww];
                float a = (mwv == NEG_INF) ? 0.f : __expf(mwv - M);
                lt += a * lw[ww];
                r0 += a * accL[ww][d0];
                r1 += a * accL[ww][d0 + 1];
            }
            float inv = lt > 0.f ? 1.f / lt : 0.f;   // empty graph -> r = 0
            A[(size_t)b * KQ + DIN + d0]     = f2b(r0 * inv);
            A[(size_t)b * KQ + DIN + d0 + 1] = f2b(r1 * inv);
        }
    }
}

// ---------------------------------------------------------------------------
// Prep: fused weight W' = Wih (+Whh on k<512), rows permuted to the
// gate-interleaved layout nn = (d>>4)*64 + g*16 + (d&15); bias likewise.
// Wpost -> bf16. All reads dtype-dispatched via flags.
// ---------------------------------------------------------------------------
__global__ void prep_weights(const ushort_t* __restrict__ Wih,
                             const ushort_t* __restrict__ Whh,
                             const ushort_t* __restrict__ bih,
                             const ushort_t* __restrict__ bhh,
                             const ushort_t* __restrict__ Wpost,
                             const ushort_t* __restrict__ bpost,
                             ushort_t* __restrict__ Wp,
                             float* __restrict__ bias2,
                             float* __restrict__ biaspost,
                             ushort_t* __restrict__ Wpb,
                             const int* __restrict__ flags)
{
    const int idx = blockIdx.x * 256 + threadIdx.x;
    const int fWih = flags[1], fWhh = flags[2], fbih = flags[3];
    const int fbhh = flags[4], fWpo = flags[5], fbpo = flags[6];

    if (idx < NGATE * KQ) {
        const int nn = idx >> 10;
        const int k  = idx & 1023;
        const int g  = (nn >> 4) & 3;
        const int n  = g * 512 + (nn >> 6) * 16 + (nn & 15);
        const int widx = n * KQ + k;
        float v = fWih ? ((const float*)Wih)[widx] : b2f(Wih[widx]);
        if (k < DIN) {
            int hidx = n * DIN + k;
            v += fWhh ? ((const float*)Whh)[hidx] : b2f(Whh[hidx]);
        }
        Wp[idx] = f2b(v);
    }
    if (idx < DOUT * KQ) {
        Wpb[idx] = fWpo ? f2b(((const float*)Wpost)[idx]) : Wpost[idx];
    }
    if (idx < NGATE) {
        const int g = (idx >> 4) & 3;
        const int n = g * 512 + (idx >> 6) * 16 + (idx & 15);
        float v1 = fbih ? ((const float*)bih)[n] : b2f(bih[n]);
        float v2 = fbhh ? ((const float*)bhh)[n] : b2f(bhh[n]);
        bias2[idx] = v1 + v2;
    }
    if (idx < DOUT) {
        biaspost[idx] = fbpo ? ((const float*)bpost)[idx] : b2f(bpost[idx]);
    }
}

// CSR offsets from sorted batch; handles int32 or int64 batch.
__global__ void prep_offsets(const int* __restrict__ batch, int* __restrict__ offs, int Nn)
{
    int n = blockIdx.x * 256 + threadIdx.x;
    if (n >= Nn) return;
    const bool is64 = batch[Nn - 1] < batch[Nn - 2];
    int cur  = is64 ? batch[2 * n] : batch[n];
    int prev = (n == 0) ? -1 : (is64 ? batch[2 * (n - 1)] : batch[n - 1]);
    for (int bb = prev + 1; bb <= cur; ++bb) offs[bb] = n;
    if (n == Nn - 1) {
        for (int bb = cur + 1; bb <= BGR; ++bb) offs[bb] = Nn;
    }
}

// ---------------------------------------------------------------------------
extern "C" void kernel_launch(void* const* d_in, const int* in_sizes, int n_in,
                              void* d_out, int out_size, void* d_ws, size_t ws_size,
                              hipStream_t stream)
{
    const ushort_t* x     = (const ushort_t*)d_in[0];
    const int*      batch = (const int*)d_in[1];
    const ushort_t* Wih   = (const ushort_t*)d_in[2];
    const ushort_t* Whh   = (const ushort_t*)d_in[3];
    const ushort_t* bih   = (const ushort_t*)d_in[4];
    const ushort_t* bhh   = (const ushort_t*)d_in[5];
    const ushort_t* Wpost = (const ushort_t*)d_in[6];
    const ushort_t* bpost = (const ushort_t*)d_in[7];
    const int Nn = in_sizes[1];
    const long long Tx = (long long)in_sizes[0];   // Nn * DIN elements

    char* p = (char*)d_ws;
    auto carve = [&](size_t bytes) -> void* {
        char* q = p;
        p += (bytes + 255) & ~(size_t)255;
        return (void*)q;
    };
    ushort_t* Wp       = (ushort_t*)carve((size_t)NGATE * KQ * 2);  // 4 MB
    ushort_t* Wpb      = (ushort_t*)carve((size_t)DOUT * KQ * 2);   // 1 MB
    float*    bias2    = (float*)carve((size_t)NGATE * 4);
    float*    biaspost = (float*)carve((size_t)DOUT * 4);
    float*    c        = (float*)carve((size_t)BGR * DIN * 4);      // 2 MB
    float*    H        = (float*)carve((size_t)BGR * DIN * 4);      // 2 MB
    ushort_t* A        = (ushort_t*)carve((size_t)BGR * KQ * 2);    // 2 MB
    int*      offs     = (int*)carve((size_t)(BGR + 1) * 4);
    int*      flags    = (int*)carve(16 * 4);
    size_t used = (size_t)(p - (char*)d_ws);
    const bool use_xb = (ws_size >= used + (size_t)Tx * 2 + 256);
    ushort_t* xb = use_xb ? (ushort_t*)carve((size_t)Tx * 2) : nullptr;

    probe_dtypes<<<1, 256, 0, stream>>>(x, Wih, Whh, bih, bhh, Wpost, bpost, flags);
    prep_weights<<<(NGATE * KQ) / 256, 256, 0, stream>>>(
        Wih, Whh, bih, bhh, Wpost, bpost, Wp, bias2, biaspost, Wpb, flags);
    prep_offsets<<<(Nn + 255) / 256, 256, 0, stream>>>(batch, offs, Nn);

    int use_xb_i = use_xb ? 1 : 0;
    void* args[] = {
        (void*)&x, (void*)&xb, (void*)&offs, (void*)&Wp, (void*)&bias2,
        (void*)&bih, (void*)&bhh, (void*)&c, (void*)&H, (void*)&A,
        (void*)&flags, (void*)&use_xb_i
    };
    hipLaunchCooperativeKernel((const void*)fused_loop, dim3(512), dim3(256),
                               args, 0, stream);

    gemm_bt<1><<<dim3(DOUT / BN, BGR / BM), 256, 0, stream>>>(
        A, Wpb, biaspost, (float*)d_out, BGR, DOUT, KQ);
}

// Round 3
// 530.637 us; speedup vs baseline: 2.3023x; 2.3023x over previous
//
#include <hip/hip_runtime.h>
#include <stdint.h>
#include <stddef.h>

#define DIN    512
#define BGR    1024
#define NGATE  2048   // 4*DIN
#define KQ     1024   // 2*DIN (q_star width)
#define DOUT   512
#define TSTEPS 6

typedef unsigned short ushort_t;
typedef short bf16x8 __attribute__((ext_vector_type(8)));
typedef unsigned short u16x8 __attribute__((ext_vector_type(8)));
typedef float f32x4 __attribute__((ext_vector_type(4)));

__device__ __forceinline__ float b2f(unsigned short u) {
    unsigned int i = ((unsigned int)u) << 16;
    float f;
    __builtin_memcpy(&f, &i, 4);
    return f;
}

__device__ __forceinline__ unsigned short f2b(float f) {
    unsigned int i;
    __builtin_memcpy(&i, &f, 4);
    unsigned int lsb = (i >> 16) & 1u;
    i += 0x7fffu + lsb;   // round-to-nearest-even
    return (unsigned short)(i >> 16);
}

__device__ __forceinline__ float fast_sigmoid(float v) {
    return 1.f / (1.f + __expf(-v));
}

__device__ __forceinline__ float fast_tanh(float v) {
    float t = fabsf(v);
    float e = __expf(-2.f * t);
    float r = (1.f - e) / (1.f + e);
    return v < 0.f ? -r : r;
}

// Direct global->LDS 16B copy (CK-style addrspace cast via uintptr_t).
// LDS dest is wave-uniform base; HW writes lane l's 16B at base + l*16.
__device__ __forceinline__ void gld_lds16(const ushort_t* g, ushort_t* l) {
    auto const* gp = reinterpret_cast<const unsigned int __attribute__((address_space(1)))*>(
        reinterpret_cast<uintptr_t>(g));
    auto* lp = reinterpret_cast<unsigned int __attribute__((address_space(3)))*>(
        reinterpret_cast<uintptr_t>(l));
    __builtin_amdgcn_global_load_lds(gp, lp, 16, 0, 0);
}

#define BM 64
#define BN 64
#define BK 32

// ---------------------------------------------------------------------------
// Fused z-GEMM + LSTM cell. Weights gate-interleaved:
//   nn = (d>>4)*64 + g*16 + (d&15)  maps original row n = g*512 + d.
// Block = 64 rows x 64 gate-cols, BK=64, 4 waves (wave w owns rows 16w..16w+15;
// acc[ni] = gate ni). Staging via global_load_lds with XOR-swizzled source:
// logical (row, col8) lands at LDS col8 ^ (row&7); frag reads apply same XOR
// -> ds_read_b128 spreads across banks instead of 8/16-way conflicting.
// Epilogue computes c,h in-register; z never touches memory. Bit-identical
// MFMA order to the R1 kernel.
// ---------------------------------------------------------------------------
__global__ __launch_bounds__(256)
void gemm_cell(const ushort_t* __restrict__ Ag,   // q_star [1024][1024] bf16
               const ushort_t* __restrict__ Wg,   // Wp2 [2048][1024] bf16
               const float* __restrict__ bias2,   // gate-interleaved bias
               float* __restrict__ c, float* __restrict__ H)
{
    __shared__ __align__(16) ushort_t As[64 * 64];   // 8 KB
    __shared__ __align__(16) ushort_t Bs[64 * 64];   // 8 KB

    const int tid  = threadIdx.x;
    const int lane = tid & 63;
    const int w    = tid >> 6;
    const int lrow = lane & 15;
    const int quad = lane >> 4;

    const int n0 = blockIdx.x * 64;   // Wp2 row block (dim-block * 64)
    const int m0 = blockIdx.y * 64;

    // staging geometry: per gld, lane l -> tile row (l>>3), swizzled col
    const int r8  = lane >> 3;                     // 0..7
    const int csw = 8 * ((lane & 7) ^ r8);         // swizzled source col (elems)

    const ushort_t* aS0 = Ag + (size_t)(m0 + w * 16 + r8) * KQ + csw;
    const ushort_t* aS1 = Ag + (size_t)(m0 + w * 16 + 8 + r8) * KQ + csw;
    const ushort_t* bS0 = Wg + (size_t)(n0 + w * 16 + r8) * KQ + csw;
    const ushort_t* bS1 = Wg + (size_t)(n0 + w * 16 + 8 + r8) * KQ + csw;
    ushort_t* aL0 = As + w * 1024;
    ushort_t* aL1 = As + w * 1024 + 512;
    ushort_t* bL0 = Bs + w * 1024;
    ushort_t* bL1 = Bs + w * 1024 + 512;

    f32x4 acc4[4];
#pragma unroll
    for (int ni = 0; ni < 4; ni++) acc4[ni] = (f32x4){0.f, 0.f, 0.f, 0.f};

    const int rx = lrow & 7;   // read-side swizzle key

    for (int kt = 0; kt < KQ; kt += 64) {
        __syncthreads();
        gld_lds16(aS0 + kt, aL0);
        gld_lds16(aS1 + kt, aL1);
        gld_lds16(bS0 + kt, bL0);
        gld_lds16(bS1 + kt, bL1);
        __syncthreads();   // compiler drains vmcnt(0) before barrier

#pragma unroll
        for (int ks = 0; ks < 2; ks++) {
            const int coff = 8 * ((ks * 4 + quad) ^ rx);
            bf16x8 af = *(const bf16x8*)&As[(w * 16 + lrow) * 64 + coff];
            bf16x8 bfr[4];
#pragma unroll
            for (int ni = 0; ni < 4; ni++)
                bfr[ni] = *(const bf16x8*)&Bs[(ni * 16 + lrow) * 64 + coff];
#pragma unroll
            for (int ni = 0; ni < 4; ni++)
                acc4[ni] = __builtin_amdgcn_mfma_f32_16x16x32_bf16(
                    af, bfr[ni], acc4[ni], 0, 0, 0);
        }
    }

    // ---- fused LSTM cell epilogue (D layout: row=quad*4+r, col=lrow) ----
    const int dd  = blockIdx.x * 16 + lrow;
    const float bi_ = bias2[n0 + lrow];
    const float bf_ = bias2[n0 + 16 + lrow];
    const float bg_ = bias2[n0 + 32 + lrow];
    const float bo_ = bias2[n0 + 48 + lrow];
#pragma unroll
    for (int r = 0; r < 4; r++) {
        const int gm = m0 + w * 16 + quad * 4 + r;
        float zi = acc4[0][r] + bi_;
        float zf = acc4[1][r] + bf_;
        float zg = acc4[2][r] + bg_;
        float zo = acc4[3][r] + bo_;
        size_t off = (size_t)gm * DIN + dd;
        float cc = c[off];
        cc = fast_sigmoid(zf) * cc + fast_sigmoid(zi) * fast_tanh(zg);
        float hh = fast_sigmoid(zo) * fast_tanh(cc);
        c[off] = cc;
        H[off] = hh;
    }
}

// ---------------------------------------------------------------------------
// Plain GEMM 64x64 tile (final Wpost + relu only). Reg-staged, unchanged
// from the verified R1 kernel (known-good control for the output path).
// ---------------------------------------------------------------------------
template <int MODE>
__global__ __launch_bounds__(256)
void gemm_bt(const ushort_t* __restrict__ Ag, const ushort_t* __restrict__ Bgm,
             const float* __restrict__ bias, float* __restrict__ Cout,
             int M, int N, int K)
{
    __shared__ __align__(16) ushort_t As[BM * BK];
    __shared__ __align__(16) ushort_t Bs[BN * BK];

    const int tid  = threadIdx.x;
    const int lane = tid & 63;
    const int w    = tid >> 6;
    const int wr   = w >> 1;
    const int wc   = w & 1;
    const int lrow = lane & 15;
    const int quad = lane >> 4;

    const int n0 = blockIdx.x * BN;
    const int m0 = blockIdx.y * BM;

    const int srow = tid >> 2;
    const int scol = (tid & 3) * 8;

    const ushort_t* aSrc = Ag  + (size_t)(m0 + srow) * K + scol;
    const ushort_t* bSrc = Bgm + (size_t)(n0 + srow) * K + scol;

    f32x4 acc[2][2];
#pragma unroll
    for (int i = 0; i < 2; i++)
#pragma unroll
        for (int j = 0; j < 2; j++)
            acc[i][j] = (f32x4){0.f, 0.f, 0.f, 0.f};

    bf16x8 av = *(const bf16x8*)(aSrc);
    bf16x8 bv = *(const bf16x8*)(bSrc);

    for (int kt = 0; kt < K; kt += BK) {
        __syncthreads();
        *(bf16x8*)&As[srow * BK + scol] = av;
        *(bf16x8*)&Bs[srow * BK + scol] = bv;
        if (kt + BK < K) {
            av = *(const bf16x8*)(aSrc + kt + BK);
            bv = *(const bf16x8*)(bSrc + kt + BK);
        }
        __syncthreads();

        bf16x8 af[2], bfr[2];
#pragma unroll
        for (int mi = 0; mi < 2; mi++)
            af[mi] = *(const bf16x8*)&As[(wr * 32 + mi * 16 + lrow) * BK + quad * 8];
#pragma unroll
        for (int ni = 0; ni < 2; ni++)
            bfr[ni] = *(const bf16x8*)&Bs[(wc * 32 + ni * 16 + lrow) * BK + quad * 8];

#pragma unroll
        for (int mi = 0; mi < 2; mi++)
#pragma unroll
            for (int ni = 0; ni < 2; ni++)
                acc[mi][ni] = __builtin_amdgcn_mfma_f32_16x16x32_bf16(
                    af[mi], bfr[ni], acc[mi][ni], 0, 0, 0);
    }

#pragma unroll
    for (int mi = 0; mi < 2; mi++) {
#pragma unroll
        for (int ni = 0; ni < 2; ni++) {
#pragma unroll
            for (int r = 0; r < 4; r++) {
                int gm = m0 + wr * 32 + mi * 16 + quad * 4 + r;
                int gn = n0 + wc * 32 + ni * 16 + lrow;
                float v = acc[mi][ni][r] + bias[gn];
                if (MODE == 1) {
                    if (!(v > 0.f) && (v == v)) v = 0.f;   // NaN-transparent relu
                }
                Cout[(size_t)gm * N + gn] = v;
            }
        }
    }
}

// ---------------------------------------------------------------------------
// One-pass online-softmax attention, 4-row interleaved (4 shuffle chains in
// flight per wave; same per-wave update order as the 2-row version ->
// bit-identical). Reads q = h from H (f32), writes q_star halves as bf16.
// XMODE 0: read bf16 from xb.  XMODE 1: t=0 — branch on flags[0], write xb.
// XMODE 2: fallback — branch read from x, no xb write.
// ---------------------------------------------------------------------------
template <int XMODE>
__global__ __launch_bounds__(256, 4)
void attn_step(const ushort_t* __restrict__ xbsrc, const ushort_t* __restrict__ xraw,
               ushort_t* __restrict__ xbdst, const int* __restrict__ offs,
               const float* __restrict__ H, ushort_t* __restrict__ A,
               const int* __restrict__ flags)
{
    const int b    = blockIdx.x;
    const int tid  = threadIdx.x;
    const int lane = tid & 63;
    const int w    = tid >> 6;
    const int xf   = (XMODE == 0) ? 0 : flags[0];   // uniform

    __shared__ float accL[4][DIN];   // 8 KB
    __shared__ float mw[4], lw[4];

    // ---- q = h: copy to q_star (bf16, packed store) + per-lane slice ----
    const float* hrow = H + (size_t)b * DIN;
    {
        const int dq = tid * 2;
        unsigned int qw = (unsigned int)f2b(hrow[dq])
                        | ((unsigned int)f2b(hrow[dq + 1]) << 16);
        *(unsigned int*)&A[(size_t)b * KQ + dq] = qw;
    }
    f32x4 q0v = *(const f32x4*)(hrow + lane * 8);
    f32x4 q1v = *(const f32x4*)(hrow + lane * 8 + 4);
    float q8[8] = {q0v[0], q0v[1], q0v[2], q0v[3], q1v[0], q1v[1], q1v[2], q1v[3]};

    const int s  = offs[b];
    const int en = offs[b + 1];

    const float NEG_INF = -__builtin_inff();
    float m = NEG_INF, l = 0.f;
    float acc[8];
#pragma unroll
    for (int j = 0; j < 8; j++) acc[j] = 0.f;

    // lane covers dims [lane*8, lane*8+8)
    auto load_row = [&](int n, float* v) {
        if (XMODE == 0 || !xf) {
            const ushort_t* src = (XMODE == 0) ? xbsrc : xraw;
            u16x8 xv = *(const u16x8*)(src + (size_t)n * DIN + lane * 8);
#pragma unroll
            for (int j = 0; j < 8; j++) v[j] = b2f(xv[j]);
            if (XMODE == 1)
                *(u16x8*)(xbdst + (size_t)n * DIN + lane * 8) = xv;
        } else {
            const float* xp = (const float*)xraw;
            f32x4 v0 = *(const f32x4*)(xp + (size_t)n * DIN + lane * 8);
            f32x4 v1 = *(const f32x4*)(xp + (size_t)n * DIN + lane * 8 + 4);
#pragma unroll
            for (int j = 0; j < 4; j++) { v[j] = v0[j]; v[4 + j] = v1[j]; }
            if (XMODE == 1) {
                u16x8 o;
#pragma unroll
                for (int j = 0; j < 8; j++) o[j] = f2b(v[j]);
                *(u16x8*)(xbdst + (size_t)n * DIN + lane * 8) = o;
            }
        }
    };

    auto update = [&](float e, const float* xv) {
        float mn = fmaxf(m, e);
        float al = __expf(m - mn);    // first node: exp(-inf)=0
        float pp = __expf(e - mn);
        l = l * al + pp;
#pragma unroll
        for (int j = 0; j < 8; j++) acc[j] = acc[j] * al + pp * xv[j];
        m = mn;
    };

    // ---- 4-row pipelined pass (rows n..n+12; prefetch n+16..n+28) ----
    float x0[8] = {0.f}, x1[8] = {0.f}, x2[8] = {0.f}, x3[8] = {0.f};
    int n = s + w;
    if (n < en)      load_row(n, x0);
    if (n + 4 < en)  load_row(n + 4, x1);
    if (n + 8 < en)  load_row(n + 8, x2);
    if (n + 12 < en) load_row(n + 12, x3);
    for (; n < en; n += 16) {
        float p0[8], p1[8], p2[8], p3[8];
        const int np = n + 16;
        if (np < en)      load_row(np, p0);
        if (np + 4 < en)  load_row(np + 4, p1);
        if (np + 8 < en)  load_row(np + 8, p2);
        if (np + 12 < en) load_row(np + 12, p3);

        float e0 = 0.f, e1 = 0.f, e2 = 0.f, e3 = 0.f;
#pragma unroll
        for (int j = 0; j < 8; j++) {
            e0 += q8[j] * x0[j];
            e1 += q8[j] * x1[j];
            e2 += q8[j] * x2[j];
            e3 += q8[j] * x3[j];
        }
#pragma unroll
        for (int off = 32; off > 0; off >>= 1) {
            e0 += __shfl_xor(e0, off, 64);
            e1 += __shfl_xor(e1, off, 64);
            e2 += __shfl_xor(e2, off, 64);
            e3 += __shfl_xor(e3, off, 64);
        }

        update(e0, x0);
        if (n + 4 < en)  update(e1, x1);
        if (n + 8 < en)  update(e2, x2);
        if (n + 12 < en) update(e3, x3);

#pragma unroll
        for (int j = 0; j < 8; j++) {
            x0[j] = p0[j]; x1[j] = p1[j]; x2[j] = p2[j]; x3[j] = p3[j];
        }
    }

    // ---- merge 4 waves (flash combine, identical to R1) ----
    if (lane == 0) { mw[w] = m; lw[w] = l; }
#pragma unroll
    for (int j = 0; j < 8; j++) accL[w][lane * 8 + j] = acc[j];
    __syncthreads();

    const float M = fmaxf(fmaxf(mw[0], mw[1]), fmaxf(mw[2], mw[3]));
    const int d0 = tid * 2;
    float r0 = 0.f, r1 = 0.f, lt = 0.f;
#pragma unroll
    for (int ww = 0; ww < 4; ww++) {
        float mwv = mw[ww];
        float a = (mwv == NEG_INF) ? 0.f : __expf(mwv - M);
        lt += a * lw[ww];
        r0 += a * accL[ww][d0];
        r1 += a * accL[ww][d0 + 1];
    }
    float inv = lt > 0.f ? 1.f / lt : 0.f;   // empty graph -> r = 0
    unsigned int rw = (unsigned int)f2b(r0 * inv)
                    | ((unsigned int)f2b(r1 * inv) << 16);
    *(unsigned int*)&A[(size_t)b * KQ + DIN + d0] = rw;
}

// ---------------------------------------------------------------------------
// One merged prep kernel (replaces probe + prep_weights + prep_h0 +
// prep_offsets). Each block re-derives the dtype flags into shared memory
// (cheap, L2-broadcast reads), then handles its global-idx slice of:
// weights fusion+permute, Wpost cast, biases, h0/c0 init, CSR offsets.
// Grid = NGATE*KQ/256 = 8192 blocks.
// ---------------------------------------------------------------------------
__global__ void prep_all(const ushort_t* __restrict__ x,
                         const ushort_t* __restrict__ Wih,
                         const ushort_t* __restrict__ Whh,
                         const ushort_t* __restrict__ bih,
                         const ushort_t* __restrict__ bhh,
                         const ushort_t* __restrict__ Wpost,
                         const ushort_t* __restrict__ bpost,
                         const int* __restrict__ batch, int Nn,
                         ushort_t* __restrict__ Wp,
                         float* __restrict__ bias2,
                         float* __restrict__ biaspost,
                         ushort_t* __restrict__ Wpb,
                         float* __restrict__ c,
                         float* __restrict__ H,
                         ushort_t* __restrict__ A,
                         int* __restrict__ offs,
                         int* __restrict__ flags)
{
    __shared__ int cnt[7];
    __shared__ int fsh[7];
    const int tid = threadIdx.x;
    if (tid < 7) cnt[tid] = 0;
    __syncthreads();
    {
        const int t = tid >> 5;
        const int l = tid & 31;
        if (t < 7) {
            const ushort_t* pp = (t == 0) ? x : (t == 1) ? Wih : (t == 2) ? Whh
                               : (t == 3) ? bih : (t == 4) ? bhh
                               : (t == 5) ? Wpost : bpost;
            int good = 0;
            for (int i = 0; i < 4; i++) {
                ushort_t u = pp[(l * 4 + i) * 2];
                int ex = (u >> 7) & 0xFF;
                if (ex == 0 || (ex >= 96 && ex <= 143)) good++;
            }
            atomicAdd(&cnt[t], good);
        }
    }
    __syncthreads();
    if (tid < 7) fsh[tid] = (cnt[tid] < 96) ? 1 : 0;
    __syncthreads();
    const int fWih = fsh[1], fWhh = fsh[2], fbih = fsh[3];
    const int fbhh = fsh[4], fWpo = fsh[5], fbpo = fsh[6];

    const int idx = blockIdx.x * 256 + tid;
    if (blockIdx.x == 0 && tid < 7) flags[tid] = fsh[tid];

    // ---- fused weight W' = Wih (+Whh on k<512), gate-interleaved rows ----
    if (idx < NGATE * KQ) {
        const int nn = idx >> 10;
        const int k  = idx & 1023;
        const int g  = (nn >> 4) & 3;
        const int n  = g * 512 + (nn >> 6) * 16 + (nn & 15);
        const int widx = n * KQ + k;
        float v = fWih ? ((const float*)Wih)[widx] : b2f(Wih[widx]);
        if (k < DIN) {
            int hidx = n * DIN + k;
            v += fWhh ? ((const float*)Whh)[hidx] : b2f(Whh[hidx]);
        }
        Wp[idx] = f2b(v);
    }
    if (idx < DOUT * KQ) {
        Wpb[idx] = fWpo ? f2b(((const float*)Wpost)[idx]) : Wpost[idx];
    }
    if (idx < NGATE) {
        const int g = (idx >> 4) & 3;
        const int n = g * 512 + (idx >> 6) * 16 + (idx & 15);
        float v1 = fbih ? ((const float*)bih)[n] : b2f(bih[n]);
        float v2 = fbhh ? ((const float*)bhh)[n] : b2f(bhh[n]);
        bias2[idx] = v1 + v2;
    }
    if (idx < DOUT) {
        biaspost[idx] = fbpo ? ((const float*)bpost)[idx] : b2f(bpost[idx]);
    }

    // ---- step-0 state: z0 = bih+bhh (same for all graphs) ----
    if (idx < BGR * DIN) {
        const int d = idx & (DIN - 1);
        float zi = fbih ? ((const float*)bih)[d] : b2f(bih[d]);
        zi      += fbhh ? ((const float*)bhh)[d] : b2f(bhh[d]);
        float zg = fbih ? ((const float*)bih)[2 * DIN + d] : b2f(bih[2 * DIN + d]);
        zg      += fbhh ? ((const float*)bhh)[2 * DIN + d] : b2f(bhh[2 * DIN + d]);
        float zo = fbih ? ((const float*)bih)[3 * DIN + d] : b2f(bih[3 * DIN + d]);
        zo      += fbhh ? ((const float*)bhh)[3 * DIN + d] : b2f(bhh[3 * DIN + d]);
        float c0 = fast_sigmoid(zi) * fast_tanh(zg);   // sig(zf)*c_prev = 0
        float h0 = fast_sigmoid(zo) * fast_tanh(c0);
        c[idx] = c0;
        H[idx] = h0;
        const int bg = idx >> 9;
        A[(size_t)bg * KQ + d]       = f2b(h0);
        A[(size_t)bg * KQ + DIN + d] = 0;
    }

    // ---- CSR offsets from sorted batch (int32 or int64) ----
    if (idx < Nn) {
        const bool is64 = batch[Nn - 1] < batch[Nn - 2];
        int cur  = is64 ? batch[2 * idx] : batch[idx];
        int prev = (idx == 0) ? -1 : (is64 ? batch[2 * (idx - 1)] : batch[idx - 1]);
        for (int bb = prev + 1; bb <= cur; ++bb) offs[bb] = idx;
        if (idx == Nn - 1) {
            for (int bb = cur + 1; bb <= BGR; ++bb) offs[bb] = Nn;
        }
    }
}

// ---------------------------------------------------------------------------
extern "C" void kernel_launch(void* const* d_in, const int* in_sizes, int n_in,
                              void* d_out, int out_size, void* d_ws, size_t ws_size,
                              hipStream_t stream)
{
    const ushort_t* x     = (const ushort_t*)d_in[0];
    const int*      batch = (const int*)d_in[1];
    const ushort_t* Wih   = (const ushort_t*)d_in[2];
    const ushort_t* Whh   = (const ushort_t*)d_in[3];
    const ushort_t* bih   = (const ushort_t*)d_in[4];
    const ushort_t* bhh   = (const ushort_t*)d_in[5];
    const ushort_t* Wpost = (const ushort_t*)d_in[6];
    const ushort_t* bpost = (const ushort_t*)d_in[7];
    const int Nn = in_sizes[1];
    const long long Tx = (long long)in_sizes[0];   // Nn * DIN elements

    char* p = (char*)d_ws;
    auto carve = [&](size_t bytes) -> void* {
        char* q = p;
        p += (bytes + 255) & ~(size_t)255;
        return (void*)q;
    };
    ushort_t* Wp       = (ushort_t*)carve((size_t)NGATE * KQ * 2);  // 4 MB
    ushort_t* Wpb      = (ushort_t*)carve((size_t)DOUT * KQ * 2);   // 1 MB
    float*    bias2    = (float*)carve((size_t)NGATE * 4);
    float*    biaspost = (float*)carve((size_t)DOUT * 4);
    float*    c        = (float*)carve((size_t)BGR * DIN * 4);      // 2 MB
    float*    H        = (float*)carve((size_t)BGR * DIN * 4);      // 2 MB
    ushort_t* A        = (ushort_t*)carve((size_t)BGR * KQ * 2);    // 2 MB
    int*      offs     = (int*)carve((size_t)(BGR + 1) * 4);
    int*      flags    = (int*)carve(16 * 4);
    size_t used = (size_t)(p - (char*)d_ws);
    const bool use_xb = (ws_size >= used + (size_t)Tx * 2 + 256);
    ushort_t* xb = use_xb ? (ushort_t*)carve((size_t)Tx * 2) : nullptr;

    prep_all<<<(NGATE * KQ) / 256, 256, 0, stream>>>(
        x, Wih, Whh, bih, bhh, Wpost, bpost, batch, Nn,
        Wp, bias2, biaspost, Wpb, c, H, A, offs, flags);

    for (int t = 0; t < TSTEPS; ++t) {
        if (t > 0)
            gemm_cell<<<dim3(NGATE / 64, BGR / 64), 256, 0, stream>>>(
                A, Wp, bias2, c, H);
        if (use_xb) {
            if (t == 0)
                attn_step<1><<<BGR, 256, 0, stream>>>(xb, x, xb, offs, H, A, flags);
            else
                attn_step<0><<<BGR, 256, 0, stream>>>(xb, x, xb, offs, H, A, flags);
        } else {
            attn_step<2><<<BGR, 256, 0, stream>>>(x, x, nullptr, offs, H, A, flags);
        }
    }
    gemm_bt<1><<<dim3(DOUT / BN, BGR / BM), 256, 0, stream>>>(
        A, Wpb, biaspost, (float*)d_out, BGR, DOUT, KQ);
}

// Round 4
// 528.506 us; speedup vs baseline: 2.3115x; 1.0040x over previous
//
#include <hip/hip_runtime.h>
#include <stdint.h>
#include <stddef.h>

#define DIN    512
#define BGR    1024
#define NGATE  2048   // 4*DIN
#define KQ     1024   // 2*DIN (q_star width)
#define DOUT   512
#define TSTEPS 6

typedef unsigned short ushort_t;
typedef short bf16x8 __attribute__((ext_vector_type(8)));
typedef unsigned short u16x8 __attribute__((ext_vector_type(8)));
typedef float f32x4 __attribute__((ext_vector_type(4)));

__device__ __forceinline__ float b2f(unsigned short u) {
    unsigned int i = ((unsigned int)u) << 16;
    float f;
    __builtin_memcpy(&f, &i, 4);
    return f;
}

__device__ __forceinline__ unsigned short f2b(float f) {
    unsigned int i;
    __builtin_memcpy(&i, &f, 4);
    unsigned int lsb = (i >> 16) & 1u;
    i += 0x7fffu + lsb;   // round-to-nearest-even
    return (unsigned short)(i >> 16);
}

__device__ __forceinline__ float fast_sigmoid(float v) {
    return 1.f / (1.f + __expf(-v));
}

__device__ __forceinline__ float fast_tanh(float v) {
    float t = fabsf(v);
    float e = __expf(-2.f * t);
    float r = (1.f - e) / (1.f + e);
    return v < 0.f ? -r : r;
}

// ---------------------------------------------------------------------------
// Fused z-GEMM + LSTM cell, v2. Weights gate-interleaved:
//   nn = (d>>4)*64 + g*16 + (d&15)  maps original row n = g*512 + d.
// Block = 64 graph-rows x 64 gate-cols, BK=64, 4 waves in 2x2 (wr=w>>1,
// wc=w&1), wave-tile 32x32 as 2x2 MFMA frags. Halves B-read redundancy vs
// the 16x64-per-wave layout (512 KB vs 640 KB LDS reads/block) and halves
// barrier count. K ascending (kt,ks) == R1 order -> z bit-identical.
// Epilogue: wc=1 waves pass their g,o accs to wc=0 via 8 KB LDS; wc=0
// computes c,h in-register, writes c (f32) and H (f32).
// ---------------------------------------------------------------------------
__global__ __launch_bounds__(256)
void gemm_cell(const ushort_t* __restrict__ Ag,   // q_star [1024][1024] bf16
               const ushort_t* __restrict__ Wg,   // Wp2 [2048][1024] bf16
               const float* __restrict__ bias2,   // gate-interleaved bias
               float* __restrict__ c, float* __restrict__ H)
{
    __shared__ __align__(16) ushort_t As[64 * 64];      // 8 KB
    __shared__ __align__(16) ushort_t Bs[64 * 64];      // 8 KB
    __shared__ float Ep[2][2][32][16];                  // 8 KB g/o exchange

    const int tid  = threadIdx.x;
    const int lane = tid & 63;
    const int w    = tid >> 6;
    const int wr   = w >> 1;
    const int wc   = w & 1;
    const int lrow = lane & 15;
    const int quad = lane >> 4;

    const int n0 = blockIdx.x * 64;   // gate-col block (dim-block * 64)
    const int m0 = blockIdx.y * 64;

    const int srow = tid >> 3;        // 0..31
    const int scol = (tid & 7) * 8;   // 0,8,..,56

    const ushort_t* aSrc = Ag + (size_t)(m0 + srow) * KQ + scol;
    const ushort_t* bSrc = Wg + (size_t)(n0 + srow) * KQ + scol;
    const size_t half = (size_t)32 * KQ;

    f32x4 acc[2][2];
#pragma unroll
    for (int i = 0; i < 2; i++)
#pragma unroll
        for (int j = 0; j < 2; j++)
            acc[i][j] = (f32x4){0.f, 0.f, 0.f, 0.f};

    bf16x8 av0 = *(const bf16x8*)(aSrc);
    bf16x8 av1 = *(const bf16x8*)(aSrc + half);
    bf16x8 bv0 = *(const bf16x8*)(bSrc);
    bf16x8 bv1 = *(const bf16x8*)(bSrc + half);

    for (int kt = 0; kt < KQ; kt += 64) {
        __syncthreads();
        *(bf16x8*)&As[srow * 64 + scol]        = av0;
        *(bf16x8*)&As[(srow + 32) * 64 + scol] = av1;
        *(bf16x8*)&Bs[srow * 64 + scol]        = bv0;
        *(bf16x8*)&Bs[(srow + 32) * 64 + scol] = bv1;
        if (kt + 64 < KQ) {                    // prefetch next K-tile
            av0 = *(const bf16x8*)(aSrc + kt + 64);
            av1 = *(const bf16x8*)(aSrc + half + kt + 64);
            bv0 = *(const bf16x8*)(bSrc + kt + 64);
            bv1 = *(const bf16x8*)(bSrc + half + kt + 64);
        }
        __syncthreads();

#pragma unroll
        for (int ks = 0; ks < 2; ks++) {
            const int g8 = (ks * 4 + quad) * 8;
            bf16x8 af[2], bfr[2];
#pragma unroll
            for (int mi = 0; mi < 2; mi++)
                af[mi] = *(const bf16x8*)&As[(wr * 32 + mi * 16 + lrow) * 64 + g8];
#pragma unroll
            for (int ni = 0; ni < 2; ni++)
                bfr[ni] = *(const bf16x8*)&Bs[(wc * 32 + ni * 16 + lrow) * 64 + g8];
#pragma unroll
            for (int mi = 0; mi < 2; mi++)
#pragma unroll
                for (int ni = 0; ni < 2; ni++)
                    acc[mi][ni] = __builtin_amdgcn_mfma_f32_16x16x32_bf16(
                        af[mi], bfr[ni], acc[mi][ni], 0, 0, 0);
        }
    }

    // ---- epilogue: wc=1 (gates g,o) -> LDS; wc=0 (gates i,f) computes ----
    if (wc == 1) {
#pragma unroll
        for (int mi = 0; mi < 2; mi++)
#pragma unroll
            for (int ni = 0; ni < 2; ni++)
#pragma unroll
                for (int r = 0; r < 4; r++)
                    Ep[wr][ni][mi * 16 + quad * 4 + r][lrow] = acc[mi][ni][r];
    }
    __syncthreads();
    if (wc == 0) {
        const int dd  = blockIdx.x * 16 + lrow;
        const float bi_ = bias2[n0 + lrow];
        const float bf_ = bias2[n0 + 16 + lrow];
        const float bg_ = bias2[n0 + 32 + lrow];
        const float bo_ = bias2[n0 + 48 + lrow];
#pragma unroll
        for (int mi = 0; mi < 2; mi++) {
#pragma unroll
            for (int r = 0; r < 4; r++) {
                const int rl = mi * 16 + quad * 4 + r;
                const int gm = m0 + wr * 32 + rl;
                float zi = acc[mi][0][r] + bi_;
                float zf = acc[mi][1][r] + bf_;
                float zg = Ep[wr][0][rl][lrow] + bg_;
                float zo = Ep[wr][1][rl][lrow] + bo_;
                size_t off = (size_t)gm * DIN + dd;
                float cc = c[off];
                cc = fast_sigmoid(zf) * cc + fast_sigmoid(zi) * fast_tanh(zg);
                float hh = fast_sigmoid(zo) * fast_tanh(cc);
                c[off] = cc;
                H[off] = hh;
            }
        }
    }
}

// ---------------------------------------------------------------------------
// Plain GEMM 64x64 tile (final Wpost + relu only). Known-good, unchanged.
// ---------------------------------------------------------------------------
#define BM 64
#define BN 64
#define BK 32

template <int MODE>
__global__ __launch_bounds__(256)
void gemm_bt(const ushort_t* __restrict__ Ag, const ushort_t* __restrict__ Bgm,
             const float* __restrict__ bias, float* __restrict__ Cout,
             int M, int N, int K)
{
    __shared__ __align__(16) ushort_t As[BM * BK];
    __shared__ __align__(16) ushort_t Bs[BN * BK];

    const int tid  = threadIdx.x;
    const int lane = tid & 63;
    const int w    = tid >> 6;
    const int wr   = w >> 1;
    const int wc   = w & 1;
    const int lrow = lane & 15;
    const int quad = lane >> 4;

    const int n0 = blockIdx.x * BN;
    const int m0 = blockIdx.y * BM;

    const int srow = tid >> 2;
    const int scol = (tid & 3) * 8;

    const ushort_t* aSrc = Ag  + (size_t)(m0 + srow) * K + scol;
    const ushort_t* bSrc = Bgm + (size_t)(n0 + srow) * K + scol;

    f32x4 acc[2][2];
#pragma unroll
    for (int i = 0; i < 2; i++)
#pragma unroll
        for (int j = 0; j < 2; j++)
            acc[i][j] = (f32x4){0.f, 0.f, 0.f, 0.f};

    bf16x8 av = *(const bf16x8*)(aSrc);
    bf16x8 bv = *(const bf16x8*)(bSrc);

    for (int kt = 0; kt < K; kt += BK) {
        __syncthreads();
        *(bf16x8*)&As[srow * BK + scol] = av;
        *(bf16x8*)&Bs[srow * BK + scol] = bv;
        if (kt + BK < K) {
            av = *(const bf16x8*)(aSrc + kt + BK);
            bv = *(const bf16x8*)(bSrc + kt + BK);
        }
        __syncthreads();

        bf16x8 af[2], bfr[2];
#pragma unroll
        for (int mi = 0; mi < 2; mi++)
            af[mi] = *(const bf16x8*)&As[(wr * 32 + mi * 16 + lrow) * BK + quad * 8];
#pragma unroll
        for (int ni = 0; ni < 2; ni++)
            bfr[ni] = *(const bf16x8*)&Bs[(wc * 32 + ni * 16 + lrow) * BK + quad * 8];

#pragma unroll
        for (int mi = 0; mi < 2; mi++)
#pragma unroll
            for (int ni = 0; ni < 2; ni++)
                acc[mi][ni] = __builtin_amdgcn_mfma_f32_16x16x32_bf16(
                    af[mi], bfr[ni], acc[mi][ni], 0, 0, 0);
    }

#pragma unroll
    for (int mi = 0; mi < 2; mi++) {
#pragma unroll
        for (int ni = 0; ni < 2; ni++) {
#pragma unroll
            for (int r = 0; r < 4; r++) {
                int gm = m0 + wr * 32 + mi * 16 + quad * 4 + r;
                int gn = n0 + wc * 32 + ni * 16 + lrow;
                float v = acc[mi][ni][r] + bias[gn];
                if (MODE == 1) {
                    if (!(v > 0.f) && (v == v)) v = 0.f;   // NaN-transparent relu
                }
                Cout[(size_t)gm * N + gn] = v;
            }
        }
    }
}

// ---------------------------------------------------------------------------
// One-pass online-softmax attention, v3: split-row reduce.
// 8 half-waves of 32 lanes; half hg owns rows == hg (mod 8); lane covers
// 16 dims. Row-dot reduce = 5 shfl_xor (offsets 16..1, stays in-half) for
// 2 rows per chain-step -> 2.4x fewer DS shuffle ops than the 64-lane
// 6-step chain. 2-row ILP + 2-row prefetch (4 rows in flight).
// 8-way flash merge via LDS. Writes q (from H) and r halves of q_star.
// XMODE 0: read bf16 from xb.  XMODE 1: t=0, branch on flags[0], write xb.
// XMODE 2: fallback, branch read from x, no xb write.
// ---------------------------------------------------------------------------
template <int XMODE>
__global__ __launch_bounds__(256, 4)
void attn_step(const ushort_t* __restrict__ xbsrc, const ushort_t* __restrict__ xraw,
               ushort_t* __restrict__ xbdst, const int* __restrict__ offs,
               const float* __restrict__ H, ushort_t* __restrict__ A,
               const int* __restrict__ flags)
{
    const int b    = blockIdx.x;
    const int tid  = threadIdx.x;
    const int hg   = tid >> 5;    // half-wave 0..7
    const int lh   = tid & 31;    // lane in half
    const int xf   = (XMODE == 0) ? 0 : flags[0];   // uniform

    __shared__ float accL[8][DIN];   // 16 KB
    __shared__ float mw[8], lw[8];

    // ---- q = h: copy to q_star (bf16, packed store) + per-lane 16-dim slice
    const float* hrow = H + (size_t)b * DIN;
    {
        const int dq = tid * 2;
        unsigned int qw = (unsigned int)f2b(hrow[dq])
                        | ((unsigned int)f2b(hrow[dq + 1]) << 16);
        *(unsigned int*)&A[(size_t)b * KQ + dq] = qw;
    }
    float q16[16];
    {
        const float* qp = hrow + lh * 16;
#pragma unroll
        for (int v4 = 0; v4 < 4; v4++) {
            f32x4 qv = *(const f32x4*)(qp + v4 * 4);
#pragma unroll
            for (int j = 0; j < 4; j++) q16[v4 * 4 + j] = qv[j];
        }
    }

    const int s  = offs[b];
    const int en = offs[b + 1];

    const float NEG_INF = -__builtin_inff();
    float m = NEG_INF, l = 0.f;
    float acc[16];
#pragma unroll
    for (int j = 0; j < 16; j++) acc[j] = 0.f;

    // lane covers dims [lh*16, lh*16+16)
    auto load_row = [&](int n, float* v) {
        if (XMODE == 0 || !xf) {
            const ushort_t* src = (XMODE == 0) ? xbsrc : xraw;
            u16x8 x0 = *(const u16x8*)(src + (size_t)n * DIN + lh * 16);
            u16x8 x1 = *(const u16x8*)(src + (size_t)n * DIN + lh * 16 + 8);
#pragma unroll
            for (int j = 0; j < 8; j++) { v[j] = b2f(x0[j]); v[8 + j] = b2f(x1[j]); }
            if (XMODE == 1) {
                *(u16x8*)(xbdst + (size_t)n * DIN + lh * 16)     = x0;
                *(u16x8*)(xbdst + (size_t)n * DIN + lh * 16 + 8) = x1;
            }
        } else {
            const float* xp = (const float*)xraw + (size_t)n * DIN + lh * 16;
#pragma unroll
            for (int v4 = 0; v4 < 4; v4++) {
                f32x4 xv = *(const f32x4*)(xp + v4 * 4);
#pragma unroll
                for (int j = 0; j < 4; j++) v[v4 * 4 + j] = xv[j];
            }
            if (XMODE == 1) {
                u16x8 o0, o1;
#pragma unroll
                for (int j = 0; j < 8; j++) { o0[j] = f2b(v[j]); o1[j] = f2b(v[8 + j]); }
                *(u16x8*)(xbdst + (size_t)n * DIN + lh * 16)     = o0;
                *(u16x8*)(xbdst + (size_t)n * DIN + lh * 16 + 8) = o1;
            }
        }
    };

    auto update = [&](float e, const float* xv) {
        float mn = fmaxf(m, e);
        float al = __expf(m - mn);    // first node: exp(-inf)=0
        float pp = __expf(e - mn);
        l = l * al + pp;
#pragma unroll
        for (int j = 0; j < 16; j++) acc[j] = acc[j] * al + pp * xv[j];
        m = mn;
    };

    // ---- 2-row pipelined pass (rows n, n+8; prefetch n+16, n+24) ----
    float xa[16] = {0.f}, xc[16] = {0.f};
    int n = s + hg;
    if (n < en)     load_row(n, xa);
    if (n + 8 < en) load_row(n + 8, xc);
    for (; n < en; n += 16) {
        float pa[16], pc[16];
        const int np = n + 16;
        if (np < en)     load_row(np, pa);
        if (np + 8 < en) load_row(np + 8, pc);

        float e1 = 0.f, e2 = 0.f;
#pragma unroll
        for (int j = 0; j < 16; j++) { e1 += q16[j] * xa[j]; e2 += q16[j] * xc[j]; }
#pragma unroll
        for (int off = 16; off > 0; off >>= 1) {
            e1 += __shfl_xor(e1, off, 64);
            e2 += __shfl_xor(e2, off, 64);
        }

        update(e1, xa);
        if (n + 8 < en) update(e2, xc);

#pragma unroll
        for (int j = 0; j < 16; j++) { xa[j] = pa[j]; xc[j] = pc[j]; }
    }

    // ---- merge 8 half-waves (flash combine) ----
    if (lh == 0) { mw[hg] = m; lw[hg] = l; }
#pragma unroll
    for (int j = 0; j < 16; j++) accL[hg][lh * 16 + j] = acc[j];
    __syncthreads();

    float M = mw[0];
#pragma unroll
    for (int hh = 1; hh < 8; hh++) M = fmaxf(M, mw[hh]);
    const int d0 = tid * 2;
    float r0 = 0.f, r1 = 0.f, lt = 0.f;
#pragma unroll
    for (int hh = 0; hh < 8; hh++) {
        float mwv = mw[hh];
        float a = (mwv == NEG_INF) ? 0.f : __expf(mwv - M);
        lt += a * lw[hh];
        r0 += a * accL[hh][d0];
        r1 += a * accL[hh][d0 + 1];
    }
    float inv = lt > 0.f ? 1.f / lt : 0.f;   // empty graph -> r = 0
    unsigned int rw = (unsigned int)f2b(r0 * inv)
                    | ((unsigned int)f2b(r1 * inv) << 16);
    *(unsigned int*)&A[(size_t)b * KQ + DIN + d0] = rw;
}

// ---------------------------------------------------------------------------
// One merged prep kernel: per-block dtype probe into shared, then global-idx
// slices of weight fusion+permute, Wpost cast, biases, h0/c0 init, offsets.
// ---------------------------------------------------------------------------
__global__ void prep_all(const ushort_t* __restrict__ x,
                         const ushort_t* __restrict__ Wih,
                         const ushort_t* __restrict__ Whh,
                         const ushort_t* __restrict__ bih,
                         const ushort_t* __restrict__ bhh,
                         const ushort_t* __restrict__ Wpost,
                         const ushort_t* __restrict__ bpost,
                         const int* __restrict__ batch, int Nn,
                         ushort_t* __restrict__ Wp,
                         float* __restrict__ bias2,
                         float* __restrict__ biaspost,
                         ushort_t* __restrict__ Wpb,
                         float* __restrict__ c,
                         float* __restrict__ H,
                         ushort_t* __restrict__ A,
                         int* __restrict__ offs,
                         int* __restrict__ flags)
{
    __shared__ int cnt[7];
    __shared__ int fsh[7];
    const int tid = threadIdx.x;
    if (tid < 7) cnt[tid] = 0;
    __syncthreads();
    {
        const int t = tid >> 5;
        const int l = tid & 31;
        if (t < 7) {
            const ushort_t* pp = (t == 0) ? x : (t == 1) ? Wih : (t == 2) ? Whh
                               : (t == 3) ? bih : (t == 4) ? bhh
                               : (t == 5) ? Wpost : bpost;
            int good = 0;
            for (int i = 0; i < 4; i++) {
                ushort_t u = pp[(l * 4 + i) * 2];
                int ex = (u >> 7) & 0xFF;
                if (ex == 0 || (ex >= 96 && ex <= 143)) good++;
            }
            atomicAdd(&cnt[t], good);
        }
    }
    __syncthreads();
    if (tid < 7) fsh[tid] = (cnt[tid] < 96) ? 1 : 0;
    __syncthreads();
    const int fWih = fsh[1], fWhh = fsh[2], fbih = fsh[3];
    const int fbhh = fsh[4], fWpo = fsh[5], fbpo = fsh[6];

    const int idx = blockIdx.x * 256 + tid;
    if (blockIdx.x == 0 && tid < 7) flags[tid] = fsh[tid];

    if (idx < NGATE * KQ) {
        const int nn = idx >> 10;
        const int k  = idx & 1023;
        const int g  = (nn >> 4) & 3;
        const int n  = g * 512 + (nn >> 6) * 16 + (nn & 15);
        const int widx = n * KQ + k;
        float v = fWih ? ((const float*)Wih)[widx] : b2f(Wih[widx]);
        if (k < DIN) {
            int hidx = n * DIN + k;
            v += fWhh ? ((const float*)Whh)[hidx] : b2f(Whh[hidx]);
        }
        Wp[idx] = f2b(v);
    }
    if (idx < DOUT * KQ) {
        Wpb[idx] = fWpo ? f2b(((const float*)Wpost)[idx]) : Wpost[idx];
    }
    if (idx < NGATE) {
        const int g = (idx >> 4) & 3;
        const int n = g * 512 + (idx >> 6) * 16 + (idx & 15);
        float v1 = fbih ? ((const float*)bih)[n] : b2f(bih[n]);
        float v2 = fbhh ? ((const float*)bhh)[n] : b2f(bhh[n]);
        bias2[idx] = v1 + v2;
    }
    if (idx < DOUT) {
        biaspost[idx] = fbpo ? ((const float*)bpost)[idx] : b2f(bpost[idx]);
    }

    // ---- step-0 state: z0 = bih+bhh (same for all graphs) ----
    if (idx < BGR * DIN) {
        const int d = idx & (DIN - 1);
        float zi = fbih ? ((const float*)bih)[d] : b2f(bih[d]);
        zi      += fbhh ? ((const float*)bhh)[d] : b2f(bhh[d]);
        float zg = fbih ? ((const float*)bih)[2 * DIN + d] : b2f(bih[2 * DIN + d]);
        zg      += fbhh ? ((const float*)bhh)[2 * DIN + d] : b2f(bhh[2 * DIN + d]);
        float zo = fbih ? ((const float*)bih)[3 * DIN + d] : b2f(bih[3 * DIN + d]);
        zo      += fbhh ? ((const float*)bhh)[3 * DIN + d] : b2f(bhh[3 * DIN + d]);
        float c0 = fast_sigmoid(zi) * fast_tanh(zg);   // sig(zf)*c_prev = 0
        float h0 = fast_sigmoid(zo) * fast_tanh(c0);
        c[idx] = c0;
        H[idx] = h0;
        const int bg = idx >> 9;
        A[(size_t)bg * KQ + d]       = f2b(h0);
        A[(size_t)bg * KQ + DIN + d] = 0;
    }

    // ---- CSR offsets from sorted batch (int32 or int64) ----
    if (idx < Nn) {
        const bool is64 = batch[Nn - 1] < batch[Nn - 2];
        int cur  = is64 ? batch[2 * idx] : batch[idx];
        int prev = (idx == 0) ? -1 : (is64 ? batch[2 * (idx - 1)] : batch[idx - 1]);
        for (int bb = prev + 1; bb <= cur; ++bb) offs[bb] = idx;
        if (idx == Nn - 1) {
            for (int bb = cur + 1; bb <= BGR; ++bb) offs[bb] = Nn;
        }
    }
}

// ---------------------------------------------------------------------------
extern "C" void kernel_launch(void* const* d_in, const int* in_sizes, int n_in,
                              void* d_out, int out_size, void* d_ws, size_t ws_size,
                              hipStream_t stream)
{
    const ushort_t* x     = (const ushort_t*)d_in[0];
    const int*      batch = (const int*)d_in[1];
    const ushort_t* Wih   = (const ushort_t*)d_in[2];
    const ushort_t* Whh   = (const ushort_t*)d_in[3];
    const ushort_t* bih   = (const ushort_t*)d_in[4];
    const ushort_t* bhh   = (const ushort_t*)d_in[5];
    const ushort_t* Wpost = (const ushort_t*)d_in[6];
    const ushort_t* bpost = (const ushort_t*)d_in[7];
    const int Nn = in_sizes[1];
    const long long Tx = (long long)in_sizes[0];   // Nn * DIN elements

    char* p = (char*)d_ws;
    auto carve = [&](size_t bytes) -> void* {
        char* q = p;
        p += (bytes + 255) & ~(size_t)255;
        return (void*)q;
    };
    ushort_t* Wp       = (ushort_t*)carve((size_t)NGATE * KQ * 2);  // 4 MB
    ushort_t* Wpb      = (ushort_t*)carve((size_t)DOUT * KQ * 2);   // 1 MB
    float*    bias2    = (float*)carve((size_t)NGATE * 4);
    float*    biaspost = (float*)carve((size_t)DOUT * 4);
    float*    c        = (float*)carve((size_t)BGR * DIN * 4);      // 2 MB
    float*    H        = (float*)carve((size_t)BGR * DIN * 4);      // 2 MB
    ushort_t* A        = (ushort_t*)carve((size_t)BGR * KQ * 2);    // 2 MB
    int*      offs     = (int*)carve((size_t)(BGR + 1) * 4);
    int*      flags    = (int*)carve(16 * 4);
    size_t used = (size_t)(p - (char*)d_ws);
    const bool use_xb = (ws_size >= used + (size_t)Tx * 2 + 256);
    ushort_t* xb = use_xb ? (ushort_t*)carve((size_t)Tx * 2) : nullptr;

    prep_all<<<(NGATE * KQ) / 256, 256, 0, stream>>>(
        x, Wih, Whh, bih, bhh, Wpost, bpost, batch, Nn,
        Wp, bias2, biaspost, Wpb, c, H, A, offs, flags);

    for (int t = 0; t < TSTEPS; ++t) {
        if (t > 0)
            gemm_cell<<<dim3(NGATE / 64, BGR / 64), 256, 0, stream>>>(
                A, Wp, bias2, c, H);
        if (use_xb) {
            if (t == 0)
                attn_step<1><<<BGR, 256, 0, stream>>>(xb, x, xb, offs, H, A, flags);
            else
                attn_step<0><<<BGR, 256, 0, stream>>>(xb, x, xb, offs, H, A, flags);
        } else {
            attn_step<2><<<BGR, 256, 0, stream>>>(x, x, nullptr, offs, H, A, flags);
        }
    }
    gemm_bt<1><<<dim3(DOUT / BN, BGR / BM), 256, 0, stream>>>(
        A, Wpb, biaspost, (float*)d_out, BGR, DOUT, KQ);
}